// Round 5
// baseline (388.669 us; speedup 1.0000x reference)
//
#include <hip/hip_runtime.h>
#include <hip/hip_bf16.h>
#include <cstddef>
#include <cstdint>

// Problem dims (fixed by setup_inputs)
#define NB   32
#define LSEQ 1024
#define HDIM 1280
#define PDIM 128

typedef unsigned short ushort_t;
typedef __bf16 bf16x8 __attribute__((ext_vector_type(8)));
typedef float  f32x4  __attribute__((ext_vector_type(4)));

// ws layout (bytes):
//   [0, 128)    : accb (32 floats)
//   [128, 136)  : sums[2] (lossSum, okSum)
//   [256, ...)  : wT bf16 [128][1280]
//   [E_OFF,...) : e bf16 [32768][128]
#define WT_OFF  256
#define E_OFF   (256 + HDIM * PDIM * 2)

__device__ __forceinline__ ushort_t bf16_rne(float x) {
  unsigned u = __float_as_uint(x);
  unsigned r = u + 0x7fffu + ((u >> 16) & 1u);
  return (ushort_t)(r >> 16);
}

// ---------------------------------------------------------------------------
// k0: wT[n][k] = bf16(w[k][n]); block 0 zeroes accb + sums (floats 0..63).
// ---------------------------------------------------------------------------
__global__ __launch_bounds__(256) void k0_wt(const float* __restrict__ pw,
                                             ushort_t* __restrict__ wT,
                                             float* __restrict__ wsf) {
  if (blockIdx.x == 0 && threadIdx.x < 64) wsf[threadIdx.x] = 0.0f;
  const int idx = blockIdx.x * 256 + threadIdx.x;
  const int k = idx >> 7, n = idx & 127;
  wT[(size_t)n * HDIM + k] = bf16_rne(pw[(size_t)k * PDIM + n]);
}

// ---------------------------------------------------------------------------
// k1: e = normalize(hs @ w + b), bf16 out.  MFMA 16x16x32.
// K-split-in-block: 4 waves share the same 16 rows; wave w owns K-chunk
// [w*320, w*320+320). Grid = 2048 blocks -> ~16 waves/CU; each wave keeps
// a K=32 register double-buffer in flight -> >=32 KB outstanding per CU
// (BW-paced, no K-loop barriers, no staging LDS). Partials combined via a
// 16 KB LDS tree, then per-row norm + bf16 store.
// ---------------------------------------------------------------------------
__global__ __launch_bounds__(256, 4) void k1_mfma(const float* __restrict__ hs,
                                                  const ushort_t* __restrict__ wT,
                                                  const float* __restrict__ pb,
                                                  ushort_t* __restrict__ e) {
  __shared__ float part[2][16][128];  // 16 KB

  const int tid = threadIdx.x;
  const int l = tid & 63, w = tid >> 6;
  const int lm = l & 15, lq = l >> 4;
  const int m0 = blockIdx.x * 16;
  const int k0 = w * 320;

  f32x4 acc[8];
#pragma unroll
  for (int t = 0; t < 8; ++t) acc[t] = (f32x4){0.f, 0.f, 0.f, 0.f};

  const float*    arow = hs + (size_t)(m0 + lm) * HDIM + k0 + lq * 8;
  const ushort_t* brow = wT + (size_t)lm * HDIM + k0 + lq * 8;

  float4 c0 = *(const float4*)(arow);
  float4 c1 = *(const float4*)(arow + 4);

#pragma unroll 2
  for (int s = 0; s < 10; ++s) {
    float4 n0, n1;
    if (s < 9) {
      n0 = *(const float4*)(arow + (s + 1) * 32);
      n1 = *(const float4*)(arow + (s + 1) * 32 + 4);
    }
    union { bf16x8 v; ushort_t u[8]; } A;
    A.u[0] = bf16_rne(c0.x); A.u[1] = bf16_rne(c0.y);
    A.u[2] = bf16_rne(c0.z); A.u[3] = bf16_rne(c0.w);
    A.u[4] = bf16_rne(c1.x); A.u[5] = bf16_rne(c1.y);
    A.u[6] = bf16_rne(c1.z); A.u[7] = bf16_rne(c1.w);
#pragma unroll
    for (int t = 0; t < 8; ++t) {
      const bf16x8 B = *(const bf16x8*)(brow + (size_t)t * 16 * HDIM + s * 32);
      acc[t] = __builtin_amdgcn_mfma_f32_16x16x32_bf16(A.v, B, acc[t], 0, 0, 0);
    }
    c0 = n0; c1 = n1;
  }

  // combine 4 K-partials: waves 0,1 write; waves 2,3 add.
  if (w < 2) {
#pragma unroll
    for (int t = 0; t < 8; ++t)
#pragma unroll
      for (int r = 0; r < 4; ++r)
        part[w][lq * 4 + r][t * 16 + lm] = acc[t][r];
  }
  __syncthreads();
  if (w >= 2) {
#pragma unroll
    for (int t = 0; t < 8; ++t)
#pragma unroll
      for (int r = 0; r < 4; ++r)
        part[w - 2][lq * 4 + r][t * 16 + lm] += acc[t][r];
  }
  __syncthreads();

  // epilogue: wave w handles rows w*4 + lq
  const int row = w * 4 + lq;
  float val[8];
  float s2 = 0.f;
#pragma unroll
  for (int t = 0; t < 8; ++t) {
    val[t] = part[0][row][t * 16 + lm] + part[1][row][t * 16 + lm] +
             pb[t * 16 + lm];
    s2 = fmaf(val[t], val[t], s2);
  }
  s2 += __shfl_xor(s2, 1, 64);
  s2 += __shfl_xor(s2, 2, 64);
  s2 += __shfl_xor(s2, 4, 64);
  s2 += __shfl_xor(s2, 8, 64);
  const float inv = 1.0f / sqrtf(s2);
#pragma unroll
  for (int t = 0; t < 8; ++t)
    e[(size_t)(m0 + row) * PDIM + t * 16 + lm] = bf16_rne(val[t] * inv);
}

// ---------------------------------------------------------------------------
// k2: flash-style loss. Block = (batch, 16-anchor tile); 4 waves split the
// j range. Softmax stats accumulate in registers off the MFMA C-fragment
// (no S tile; |sv| <= 14.3 so unshifted exp is fp32-safe). One-tile
// software prefetch of B-frags + mask/labels.
// ---------------------------------------------------------------------------
__global__ __launch_bounds__(256, 4) void k2_loss(const ushort_t* __restrict__ e,
                                                  const int* __restrict__ mask,
                                                  const int* __restrict__ labels,
                                                  float* __restrict__ accb) {
  __shared__ float part[4][16][3];

  const int tid = threadIdx.x;
  const int l = tid & 63, w = tid >> 6;
  const int b  = blockIdx.x >> 6;
  const int i0 = (blockIdx.x & 63) << 4;
  const int lm = l & 15, lq = l >> 4;

  const ushort_t* eb   = e + (size_t)b * LSEQ * PDIM;
  const int*      mrow = mask + b * LSEQ;
  const int*      lrow = labels + b * LSEQ;

  bf16x8 af[4];
  {
    const ushort_t* aptr = eb + (size_t)(i0 + lm) * PDIM + lq * 8;
#pragma unroll
    for (int c = 0; c < 4; ++c) af[c] = *(const bf16x8*)(aptr + c * 32);
  }

  int  li[4], ar[4];
  bool vi[4];
#pragma unroll
  for (int r = 0; r < 4; ++r) {
    ar[r] = i0 + lq * 4 + r;
    li[r] = lrow[ar[r]];
    vi[r] = (mrow[ar[r]] != 0) && (li[r] != -100);
  }

  float d[4] = {0.f, 0.f, 0.f, 0.f};
  float ps[4] = {0.f, 0.f, 0.f, 0.f};
  float pc[4] = {0.f, 0.f, 0.f, 0.f};
  const float invT = 1.0f / 0.07f;

  // prefetch tile 0
  int jt = w * 16;
  bf16x8 Bc[4];
  int ljc, mjc;
  {
    const int j = jt * 16 + lm;
    const ushort_t* bptr = eb + (size_t)j * PDIM + lq * 8;
#pragma unroll
    for (int c = 0; c < 4; ++c) Bc[c] = *(const bf16x8*)(bptr + c * 32);
    ljc = lrow[j];
    mjc = mrow[j];
  }

#pragma unroll 1
  for (int s = 0; s < 16; ++s, ++jt) {
    bf16x8 Bn[4];
    int ljn = 0, mjn = 0;
    if (s < 15) {
      const int jn = (jt + 1) * 16 + lm;
      const ushort_t* bptr = eb + (size_t)jn * PDIM + lq * 8;
#pragma unroll
      for (int c = 0; c < 4; ++c) Bn[c] = *(const bf16x8*)(bptr + c * 32);
      ljn = lrow[jn];
      mjn = mrow[jn];
    }

    f32x4 acc = (f32x4){0.f, 0.f, 0.f, 0.f};
#pragma unroll
    for (int c = 0; c < 4; ++c)
      acc = __builtin_amdgcn_mfma_f32_16x16x32_bf16(af[c], Bc[c], acc, 0, 0, 0);

    const int j = jt * 16 + lm;
    const bool cvj = (mjc != 0) && (ljc != -100);
#pragma unroll
    for (int r = 0; r < 4; ++r) {
      const float sv = acc[r] * invT;
      const bool dm  = cvj && (j != ar[r]);
      const float ex = __expf(sv);
      d[r] += dm ? ex : 0.f;
      const bool pos = dm && (ljc == li[r]) && vi[r];
      ps[r] += pos ? sv : 0.f;
      pc[r] += pos ? 1.f : 0.f;
    }

#pragma unroll
    for (int c = 0; c < 4; ++c) Bc[c] = Bn[c];
    ljc = ljn; mjc = mjn;
  }

#pragma unroll
  for (int r = 0; r < 4; ++r) {
#pragma unroll
    for (int off = 1; off < 16; off <<= 1) {
      d[r]  += __shfl_xor(d[r], off, 64);
      ps[r] += __shfl_xor(ps[r], off, 64);
      pc[r] += __shfl_xor(pc[r], off, 64);
    }
  }
  if (lm == 0) {
#pragma unroll
    for (int r = 0; r < 4; ++r) {
      part[w][lq * 4 + r][0] = d[r];
      part[w][lq * 4 + r][1] = ps[r];
      part[w][lq * 4 + r][2] = pc[r];
    }
  }
  __syncthreads();

  if (tid < 16) {
    float D = 0.f, P = 0.f, C = 0.f;
#pragma unroll
    for (int w2 = 0; w2 < 4; ++w2) {
      D += part[w2][tid][0];
      P += part[w2][tid][1];
      C += part[w2][tid][2];
    }
    const float logD = logf(D + 1e-12f);
    float al = (P - C * logD) / (C + 1e-12f);
#pragma unroll
    for (int off = 1; off < 16; off <<= 1) al += __shfl_xor(al, off, 64);
    if (tid == 0) atomicAdd(&accb[b], al);
  }
}

// ---------------------------------------------------------------------------
// k2b: per-batch finalize (32 blocks). cm = sum(mask), cv = valid count;
// atomicAdd the batch's loss and seq_ok into sums[2].
// ---------------------------------------------------------------------------
__global__ __launch_bounds__(256) void k2b_batch(const int* __restrict__ mask,
                                                 const int* __restrict__ labels,
                                                 const float* __restrict__ accb,
                                                 float* __restrict__ sums) {
  __shared__ int scm[4], scv[4];
  const int b = blockIdx.x;
  const int tid = threadIdx.x;
  const int l = tid & 63, w = tid >> 6;

  const int base = b * LSEQ + tid * 4;
  const int4 mv = *(const int4*)(mask + base);
  const int4 lv = *(const int4*)(labels + base);
  int cm = mv.x + mv.y + mv.z + mv.w;
  int cv = ((mv.x != 0 && lv.x != -100) ? 1 : 0) +
           ((mv.y != 0 && lv.y != -100) ? 1 : 0) +
           ((mv.z != 0 && lv.z != -100) ? 1 : 0) +
           ((mv.w != 0 && lv.w != -100) ? 1 : 0);
#pragma unroll
  for (int off = 1; off < 64; off <<= 1) {
    cm += __shfl_xor(cm, off, 64);
    cv += __shfl_xor(cv, off, 64);
  }
  if (l == 0) { scm[w] = cm; scv[w] = cv; }
  __syncthreads();
  if (tid == 0) {
    const int CM = scm[0] + scm[1] + scm[2] + scm[3];
    const int CV = scv[0] + scv[1] + scv[2] + scv[3];
    const bool ok = (CM >= 2);
    const float lossb = ok ? (-accb[b] / fmaxf((float)CV, 1.0f)) : 0.0f;
    atomicAdd(&sums[0], lossb);
    atomicAdd(&sums[1], ok ? 1.0f : 0.0f);
  }
}

// ---------------------------------------------------------------------------
// k3: final divide (1 thread).
// ---------------------------------------------------------------------------
__global__ void k3_final(const float* __restrict__ sums,
                         float* __restrict__ out) {
  if (threadIdx.x == 0) out[0] = sums[0] / fmaxf(sums[1], 1.0f);
}

// ---------------------------------------------------------------------------
extern "C" void kernel_launch(void* const* d_in, const int* in_sizes, int n_in,
                              void* d_out, int out_size, void* d_ws, size_t ws_size,
                              hipStream_t stream) {
  (void)in_sizes; (void)n_in; (void)out_size; (void)ws_size;
  const float* hs     = (const float*)d_in[0];
  const float* pw     = (const float*)d_in[1];
  const float* pb     = (const float*)d_in[2];
  const int*   mask   = (const int*)d_in[3];
  const int*   labels = (const int*)d_in[4];
  float* out = (float*)d_out;

  char* wsb = (char*)d_ws;
  float*    wsf  = (float*)wsb;
  float*    accb = wsf;        // floats [0,32)
  float*    sums = wsf + 32;   // floats [32,34)
  ushort_t* wT   = (ushort_t*)(wsb + WT_OFF);
  ushort_t* e    = (ushort_t*)(wsb + E_OFF);

  k0_wt<<<(HDIM * PDIM) / 256, 256, 0, stream>>>(pw, wT, wsf);
  k1_mfma<<<(NB * LSEQ) / 16, 256, 0, stream>>>(hs, wT, pb, e);
  k2_loss<<<NB * 64, 256, 0, stream>>>(e, mask, labels, accb);
  k2b_batch<<<NB, 256, 0, stream>>>(mask, labels, accb, sums);
  k3_final<<<1, 64, 0, stream>>>(sums, out);
}

// Round 6
// 344.316 us; speedup vs baseline: 1.1288x; 1.1288x over previous
//
#include <hip/hip_runtime.h>
#include <hip/hip_bf16.h>
#include <cstddef>
#include <cstdint>

// Problem dims (fixed by setup_inputs)
#define NB   32
#define LSEQ 1024
#define HDIM 1280
#define PDIM 128

typedef unsigned short ushort_t;
typedef __bf16 bf16x8 __attribute__((ext_vector_type(8)));
typedef float  f32x4  __attribute__((ext_vector_type(4)));

// ws layout (bytes):
//   [0, 128)    : accb (32 floats)
//   [256, ...)  : wT bf16 [128][1280]
//   [E_OFF,...) : e bf16 [32768][128]
#define WT_OFF  256
#define E_OFF   (256 + HDIM * PDIM * 2)

__device__ __forceinline__ ushort_t bf16_rne(float x) {
  unsigned u = __float_as_uint(x);
  unsigned r = u + 0x7fffu + ((u >> 16) & 1u);
  return (ushort_t)(r >> 16);
}

// ---------------------------------------------------------------------------
// k0: wT[n][k] = bf16(w[k][n]); block 0 zeroes accb.
// ---------------------------------------------------------------------------
__global__ __launch_bounds__(256) void k0_wt(const float* __restrict__ pw,
                                             ushort_t* __restrict__ wT,
                                             float* __restrict__ wsf) {
  if (blockIdx.x == 0 && threadIdx.x < 64) wsf[threadIdx.x] = 0.0f;
  const int idx = blockIdx.x * 256 + threadIdx.x;
  const int k = idx >> 7, n = idx & 127;
  wT[(size_t)n * HDIM + k] = bf16_rne(pw[(size_t)k * PDIM + n]);
}

// ---------------------------------------------------------------------------
// k1: e = normalize(hs @ w + b), bf16 out.  MFMA 16x16x32.
// Phase 1: block's 16-row hs panel is ONE contiguous 80 KB region; each
// wave streams 4 rows with fully-contiguous 1 KB wave-loads (10 float4 in
// flight per thread), converts to bf16 into a 40 KB LDS panel.
// Phase 2: K-split (wave w owns K in [w*320,w*320+320)); A-frag ds_read,
// B-frags from L2-hot wT with one-step register prefetch (s=0 issued
// before the barrier). Partial-K combine in LDS (aliases dead A panel,
// padded stride 132 -> conflict-free), then row-norm + bf16 store.
// LDS = 40960 B exactly -> 4 blocks/CU.
// ---------------------------------------------------------------------------
__global__ __launch_bounds__(256, 4) void k1_mfma(const float* __restrict__ hs,
                                                  const ushort_t* __restrict__ wT,
                                                  const float* __restrict__ pb,
                                                  ushort_t* __restrict__ e) {
  __shared__ __align__(16) char smem[16 * HDIM * 2];  // 40960 B
  ushort_t* Asm  = (ushort_t*)smem;
  float*    prtf = (float*)smem;  // aliased after MFMAs complete

  const int tid = threadIdx.x;
  const int l = tid & 63, w = tid >> 6;
  const int lm = l & 15, lq = l >> 4;
  const int m0 = blockIdx.x * 16;
  const int k0 = w * 320;

  // ---- phase 2 s=0 B prefetch (independent of LDS) ----
  const ushort_t* brow = wT + (size_t)lm * HDIM + k0 + lq * 8;
  bf16x8 Bc[8], Bn[8];
#pragma unroll
  for (int t = 0; t < 8; ++t)
    Bc[t] = *(const bf16x8*)(brow + (size_t)t * 16 * HDIM);

  // ---- phase 1: stream contiguous panel ----
  const float* prow = hs + (size_t)m0 * HDIM;
#pragma unroll
  for (int half = 0; half < 2; ++half) {
    const int r0 = w * 4 + half * 2;
    float4 buf[10];
#pragma unroll
    for (int rr = 0; rr < 2; ++rr)
#pragma unroll
      for (int i = 0; i < 5; ++i)
        buf[rr * 5 + i] =
            *(const float4*)(prow + (size_t)(r0 + rr) * HDIM + i * 256 + l * 4);
#pragma unroll
    for (int rr = 0; rr < 2; ++rr)
#pragma unroll
      for (int i = 0; i < 5; ++i) {
        const float4 v = buf[rr * 5 + i];
        union { ushort_t u[4]; uint2 p; } pk;
        pk.u[0] = bf16_rne(v.x); pk.u[1] = bf16_rne(v.y);
        pk.u[2] = bf16_rne(v.z); pk.u[3] = bf16_rne(v.w);
        *(uint2*)&Asm[(size_t)(r0 + rr) * HDIM + i * 256 + l * 4] = pk.p;
      }
  }
  __syncthreads();

  // ---- phase 2: MFMA over wave's K-chunk ----
  f32x4 acc[8];
#pragma unroll
  for (int t = 0; t < 8; ++t) acc[t] = (f32x4){0.f, 0.f, 0.f, 0.f};

#pragma unroll
  for (int s = 0; s < 10; ++s) {
    if (s < 9) {
#pragma unroll
      for (int t = 0; t < 8; ++t)
        Bn[t] = *(const bf16x8*)(brow + (size_t)t * 16 * HDIM + (s + 1) * 32);
    }
    const bf16x8 A = *(const bf16x8*)&Asm[(size_t)lm * HDIM + k0 + s * 32 + lq * 8];
#pragma unroll
    for (int t = 0; t < 8; ++t)
      acc[t] = __builtin_amdgcn_mfma_f32_16x16x32_bf16(A, Bc[t], acc[t], 0, 0, 0);
#pragma unroll
    for (int t = 0; t < 8; ++t) Bc[t] = Bn[t];
  }

  // ---- combine K-partials (part aliases Asm; stride 132 = conflict-free) ----
  __syncthreads();  // all MFMAs done; Asm is dead
#define PART(pp, row, col) prtf[((pp) * 16 + (row)) * 132 + (col)]
  if (w < 2) {
#pragma unroll
    for (int t = 0; t < 8; ++t)
#pragma unroll
      for (int r = 0; r < 4; ++r)
        PART(w, lq * 4 + r, t * 16 + lm) = acc[t][r];
  }
  __syncthreads();
  if (w >= 2) {
#pragma unroll
    for (int t = 0; t < 8; ++t)
#pragma unroll
      for (int r = 0; r < 4; ++r)
        PART(w - 2, lq * 4 + r, t * 16 + lm) += acc[t][r];
  }
  __syncthreads();

  // ---- epilogue: wave w finalizes rows w*4 + lq ----
  const int row = w * 4 + lq;
  float val[8];
  float s2 = 0.f;
#pragma unroll
  for (int t = 0; t < 8; ++t) {
    val[t] = PART(0, row, t * 16 + lm) + PART(1, row, t * 16 + lm) +
             pb[t * 16 + lm];
    s2 = fmaf(val[t], val[t], s2);
  }
  s2 += __shfl_xor(s2, 1, 64);
  s2 += __shfl_xor(s2, 2, 64);
  s2 += __shfl_xor(s2, 4, 64);
  s2 += __shfl_xor(s2, 8, 64);
  const float inv = 1.0f / sqrtf(s2);
#pragma unroll
  for (int t = 0; t < 8; ++t)
    e[(size_t)(m0 + row) * PDIM + t * 16 + lm] = bf16_rne(val[t] * inv);
#undef PART
}

// ---------------------------------------------------------------------------
// k2: flash-style loss, 32 anchors (2 i-tiles) per block to double compute
// per B-load. 4 waves split the j range; softmax stats accumulate in
// registers off the MFMA C-fragment (|sv| <= 14.3, unshifted exp safe).
// ---------------------------------------------------------------------------
__global__ __launch_bounds__(256, 3) void k2_loss(const ushort_t* __restrict__ e,
                                                  const int* __restrict__ mask,
                                                  const int* __restrict__ labels,
                                                  float* __restrict__ accb) {
  __shared__ float part[4][32][3];

  const int tid = threadIdx.x;
  const int l = tid & 63, w = tid >> 6;
  const int b  = blockIdx.x >> 5;
  const int i0 = (blockIdx.x & 31) << 5;
  const int lm = l & 15, lq = l >> 4;

  const ushort_t* eb   = e + (size_t)b * LSEQ * PDIM;
  const int*      mrow = mask + b * LSEQ;
  const int*      lrow = labels + b * LSEQ;

  bf16x8 af[2][4];
#pragma unroll
  for (int ii = 0; ii < 2; ++ii) {
    const ushort_t* aptr = eb + (size_t)(i0 + ii * 16 + lm) * PDIM + lq * 8;
#pragma unroll
    for (int c = 0; c < 4; ++c) af[ii][c] = *(const bf16x8*)(aptr + c * 32);
  }

  int  li[2][4], ar[2][4];
  bool vi[2][4];
#pragma unroll
  for (int ii = 0; ii < 2; ++ii)
#pragma unroll
    for (int r = 0; r < 4; ++r) {
      ar[ii][r] = i0 + ii * 16 + lq * 4 + r;
      li[ii][r] = lrow[ar[ii][r]];
      vi[ii][r] = (mrow[ar[ii][r]] != 0) && (li[ii][r] != -100);
    }

  float d[2][4] = {}, ps[2][4] = {}, pc[2][4] = {};
  const float invT = 1.0f / 0.07f;

  // prefetch tile 0
  int jt = w * 16;
  bf16x8 Bc[4];
  int ljc, mjc;
  {
    const int j = jt * 16 + lm;
    const ushort_t* bptr = eb + (size_t)j * PDIM + lq * 8;
#pragma unroll
    for (int c = 0; c < 4; ++c) Bc[c] = *(const bf16x8*)(bptr + c * 32);
    ljc = lrow[j];
    mjc = mrow[j];
  }

#pragma unroll 1
  for (int s = 0; s < 16; ++s, ++jt) {
    bf16x8 Bn[4];
    int ljn = 0, mjn = 0;
    if (s < 15) {
      const int jn = (jt + 1) * 16 + lm;
      const ushort_t* bptr = eb + (size_t)jn * PDIM + lq * 8;
#pragma unroll
      for (int c = 0; c < 4; ++c) Bn[c] = *(const bf16x8*)(bptr + c * 32);
      ljn = lrow[jn];
      mjn = mrow[jn];
    }

    const int j = jt * 16 + lm;
    const bool cvj = (mjc != 0) && (ljc != -100);
#pragma unroll
    for (int ii = 0; ii < 2; ++ii) {
      f32x4 acc = (f32x4){0.f, 0.f, 0.f, 0.f};
#pragma unroll
      for (int c = 0; c < 4; ++c)
        acc = __builtin_amdgcn_mfma_f32_16x16x32_bf16(af[ii][c], Bc[c], acc, 0, 0, 0);
#pragma unroll
      for (int r = 0; r < 4; ++r) {
        const float sv = acc[r] * invT;
        const bool dm  = cvj && (j != ar[ii][r]);
        const float ex = __expf(sv);
        d[ii][r] += dm ? ex : 0.f;
        const bool pos = dm && (ljc == li[ii][r]) && vi[ii][r];
        ps[ii][r] += pos ? sv : 0.f;
        pc[ii][r] += pos ? 1.f : 0.f;
      }
    }

#pragma unroll
    for (int c = 0; c < 4; ++c) Bc[c] = Bn[c];
    ljc = ljn; mjc = mjn;
  }

#pragma unroll
  for (int ii = 0; ii < 2; ++ii)
#pragma unroll
    for (int r = 0; r < 4; ++r) {
#pragma unroll
      for (int off = 1; off < 16; off <<= 1) {
        d[ii][r]  += __shfl_xor(d[ii][r], off, 64);
        ps[ii][r] += __shfl_xor(ps[ii][r], off, 64);
        pc[ii][r] += __shfl_xor(pc[ii][r], off, 64);
      }
    }
  if (lm == 0) {
#pragma unroll
    for (int ii = 0; ii < 2; ++ii)
#pragma unroll
      for (int r = 0; r < 4; ++r) {
        part[w][ii * 16 + lq * 4 + r][0] = d[ii][r];
        part[w][ii * 16 + lq * 4 + r][1] = ps[ii][r];
        part[w][ii * 16 + lq * 4 + r][2] = pc[ii][r];
      }
  }
  __syncthreads();

  if (tid < 32) {
    float D = 0.f, P = 0.f, C = 0.f;
#pragma unroll
    for (int w2 = 0; w2 < 4; ++w2) {
      D += part[w2][tid][0];
      P += part[w2][tid][1];
      C += part[w2][tid][2];
    }
    const float logD = logf(D + 1e-12f);
    float al = (P - C * logD) / (C + 1e-12f);
#pragma unroll
    for (int off = 1; off < 32; off <<= 1) al += __shfl_xor(al, off, 64);
    if (tid == 0) atomicAdd(&accb[b], al);
  }
}

// ---------------------------------------------------------------------------
// k3: final scalar, single block (round-0-verified logic, int4 loads).
// ---------------------------------------------------------------------------
__global__ __launch_bounds__(1024) void k3_final(const int* __restrict__ mask,
                                                 const int* __restrict__ labels,
                                                 const float* __restrict__ accb,
                                                 float* __restrict__ out) {
  __shared__ float lossv[NB];
  __shared__ float okv[NB];
  const int t = threadIdx.x;
  const int b = t >> 5, sub = t & 31;

  int cm = 0, cv = 0;
#pragma unroll
  for (int q = 0; q < 8; ++q) {
    const int idx = b * LSEQ + q * 128 + sub * 4;
    const int4 mv = *(const int4*)(mask + idx);
    const int4 lv = *(const int4*)(labels + idx);
    cm += mv.x + mv.y + mv.z + mv.w;
    cv += ((mv.x != 0 && lv.x != -100) ? 1 : 0) +
          ((mv.y != 0 && lv.y != -100) ? 1 : 0) +
          ((mv.z != 0 && lv.z != -100) ? 1 : 0) +
          ((mv.w != 0 && lv.w != -100) ? 1 : 0);
  }
#pragma unroll
  for (int off = 16; off; off >>= 1) {
    cm += __shfl_xor(cm, off, 64);
    cv += __shfl_xor(cv, off, 64);
  }
  if (sub == 0) {
    const bool ok = (cm >= 2);
    lossv[b] = ok ? (-accb[b] / fmaxf((float)cv, 1.0f)) : 0.0f;
    okv[b]   = ok ? 1.0f : 0.0f;
  }
  __syncthreads();
  if (t < NB) {
    float lv = lossv[t], ov = okv[t];
#pragma unroll
    for (int off = 16; off; off >>= 1) {
      lv += __shfl_xor(lv, off, 64);
      ov += __shfl_xor(ov, off, 64);
    }
    if (t == 0) out[0] = lv / fmaxf(ov, 1.0f);
  }
}

// ---------------------------------------------------------------------------
extern "C" void kernel_launch(void* const* d_in, const int* in_sizes, int n_in,
                              void* d_out, int out_size, void* d_ws, size_t ws_size,
                              hipStream_t stream) {
  (void)in_sizes; (void)n_in; (void)out_size; (void)ws_size;
  const float* hs     = (const float*)d_in[0];
  const float* pw     = (const float*)d_in[1];
  const float* pb     = (const float*)d_in[2];
  const int*   mask   = (const int*)d_in[3];
  const int*   labels = (const int*)d_in[4];
  float* out = (float*)d_out;

  char* wsb = (char*)d_ws;
  float*    wsf  = (float*)wsb;
  float*    accb = wsf;  // floats [0,32)
  ushort_t* wT   = (ushort_t*)(wsb + WT_OFF);
  ushort_t* e    = (ushort_t*)(wsb + E_OFF);

  k0_wt<<<(HDIM * PDIM) / 256, 256, 0, stream>>>(pw, wT, wsf);
  k1_mfma<<<(NB * LSEQ) / 16, 256, 0, stream>>>(hs, wT, pb, e);
  k2_loss<<<NB * 32, 256, 0, stream>>>(e, mask, labels, accb);
  k3_final<<<1, 1024, 0, stream>>>(mask, labels, accb, out);
}